// Round 1
// 207.179 us; speedup vs baseline: 1.0598x; 1.0598x over previous
//
#include <hip/hip_runtime.h>

// Laplacian-kernel regression, fused, bf16 MFMA 32x32x16.
//   d2 = ||x||^2 + ||z||^2 - 2 X.Z^T ; P = exp(-sqrt(d2)/10) ; out = P @ W
// R12: latency/serialization attack on v11 (MfmaUtil 30%, neither MFMA nor
// L2 saturated -> barrier/latency bound):
//  * 32x32x16 MFMA (4061 vs 3378 FLOP/cyc/CU, half the instr count). A/B
//    frags composed from the unchanged Xf/Zf/Wf 16-row fragment layout
//    (per-frag addresses are linear: base + kw*512B).
//  * LDS time-share: R1 = X k[0,256) staged ONCE per block (prologue);
//    R2 = X k[256,512) UNION sP, h1 re-streamed per m-tile with async
//    global_load_lds issued post-PV -> lands under QK-h0; no barrier waits
//    on a fresh L2 round trip. LDS stays 66,560B -> 2 blocks/CU.
//  * depth-2 register prefetch in QK/PV; s_setprio(1) around MFMA clusters.
//  * XCD swizzle: z-chunk pinned to an XCD pair (Zf 2MB + Wf 1MB L2-resident).

using frag8  = __attribute__((ext_vector_type(8)))  short;   // 8 bf16 (4 VGPRs)
using f32x4  = __attribute__((ext_vector_type(4)))  float;
using f32x16 = __attribute__((ext_vector_type(16))) float;   // 32x32 C/D frag

constexpr int Nn = 8192, Mm = 8192, Dd = 512, Yd = 256;
constexpr int BM = 64, BN = 256;
constexpr int MCH = 4, MPER = Mm / MCH, MT = MPER / BN;    // 2048, 8
constexpr int LDP = BN + 8;    // 264 ushort row stride for sP

// Fragment-tile layout (16-row groups, unchanged from prep_v11):
// frag(g, c) = rows [16g,16g+16) x k [32c,32c+32), 512 ushorts at
// (g*KG + c)*512, element (r,k) at ushort lane16*8 + k%8 where
// lane16 = r%16 + 16*((k%32)/8).  Xf/Zf: KG=16 (K=512). Wf: rows=y, KG=256.
// A 32x32x16 A/B-frag (32 rows x 16 k) for dst lane L (r=L&31, h=L>>5) is
// one 16B chunk: g = G0 + 2*fragrow + (r>>4), c = kw>>1,
// lane16 = (r&15) + 16*(2*(kw&1)+h)  ==>  addr = base + kw*256 ushorts.

// workspace layout (bytes)
constexpr size_t OFF_XF  = 0;                               // 8 MB
constexpr size_t OFF_ZF  = OFF_XF + (size_t)Nn * Dd * 2;    // 8 MB
constexpr size_t OFF_WF  = OFF_ZF + (size_t)Mm * Dd * 2;    // 4 MB
constexpr size_t OFF_XSQ = OFF_WF + (size_t)Yd * Mm * 2;
constexpr size_t OFF_ZSQ = OFF_XSQ + (size_t)Nn * 4;
constexpr size_t WS_NEED = OFF_ZSQ + (size_t)Mm * 4;        // ~20.1 MB

__device__ __forceinline__ ushort f2bf(float f) {
    unsigned u = __builtin_bit_cast(unsigned, f);
    u += 0x7FFFu + ((u >> 16) & 1u);          // RNE (prep only)
    return (ushort)(u >> 16);
}

__device__ __forceinline__ void gload_lds16(const ushort* g, ushort* l) {
    __builtin_amdgcn_global_load_lds(
        (const __attribute__((address_space(1))) unsigned int*)(g),
        (__attribute__((address_space(3))) unsigned int*)(l), 16, 0, 0);
}

// ---- prep (LDS-tiled, coalesced) — unchanged from v11 ----
__global__ __launch_bounds__(256) void prep_v11(
    const float* __restrict__ X, const float* __restrict__ Z,
    const float* __restrict__ W, ushort* __restrict__ Xf,
    ushort* __restrict__ Zf, ushort* __restrict__ Wf,
    float* __restrict__ xsq, float* __restrict__ zsq)
{
    __shared__ float tile[8320];                  // 16x517 (X/Z) or 32x260 (W)
    __shared__ float part[256];
    const int t = threadIdx.x, b = blockIdx.x;
    if (b < 1024) {
        const int g = (b < 512) ? b : b - 512;
        const float* src = (b < 512 ? X : Z) + (size_t)g * 16 * Dd;
        ushort* dst = (b < 512 ? Xf : Zf) + (size_t)g * 16 * 512;
        float* nrm = (b < 512 ? xsq : zsq) + g * 16;
        #pragma unroll
        for (int rep = 0; rep < 8; ++rep) {       // 2048 float4, coalesced
            const int idx = rep * 256 + t;
            const int r = idx >> 7, c4 = (idx & 127) * 4;
            const float4 v = *(const float4*)(src + (size_t)r * Dd + c4);
            float* d = tile + r * 517 + c4;
            d[0] = v.x; d[1] = v.y; d[2] = v.z; d[3] = v.w;
        }
        __syncthreads();
        {
            const int r = t & 15, s0 = (t >> 4) * 32;
            float sq = 0.0f;
            #pragma unroll
            for (int k = 0; k < 32; ++k) {
                const float v = tile[r * 517 + s0 + k];
                sq += v * v;
            }
            part[t] = sq;
        }
        __syncthreads();
        if (t < 16) {
            float sq = 0.0f;
            #pragma unroll
            for (int s = 0; s < 16; ++s) sq += part[t + 16 * s];
            nrm[t] = sq;
        }
        #pragma unroll
        for (int rep = 0; rep < 4; ++rep) {       // 1024 uint4 frag writes
            const int idx = rep * 256 + t;
            const int kg = idx >> 6, w = idx & 63;
            const int l16 = w & 15, quad = w >> 4;
            const float* s = tile + l16 * 517 + kg * 32 + quad * 8;
            uint4 pk;
            pk.x = (unsigned)f2bf(s[0]) | ((unsigned)f2bf(s[1]) << 16);
            pk.y = (unsigned)f2bf(s[2]) | ((unsigned)f2bf(s[3]) << 16);
            pk.z = (unsigned)f2bf(s[4]) | ((unsigned)f2bf(s[5]) << 16);
            pk.w = (unsigned)f2bf(s[6]) | ((unsigned)f2bf(s[7]) << 16);
            *(uint4*)(dst + (size_t)kg * 512 + w * 8) = pk;
        }
    } else {
        const int zg = b - 1024;                  // 32-z stripe of W
        const float* src = W + (size_t)zg * 32 * Yd;
        #pragma unroll
        for (int rep = 0; rep < 8; ++rep) {
            const int idx = rep * 256 + t;
            const int r = idx >> 6, c4 = (idx & 63) * 4;
            const float4 v = *(const float4*)(src + (size_t)r * Yd + c4);
            float* d = tile + r * 260 + c4;
            d[0] = v.x; d[1] = v.y; d[2] = v.z; d[3] = v.w;
        }
        __syncthreads();
        #pragma unroll
        for (int rep = 0; rep < 4; ++rep) {
            const int idx = rep * 256 + t;
            const int yg = idx >> 6, w = idx & 63;
            const int l16 = w & 15, quad = w >> 4;
            const int y = yg * 16 + l16;
            ushort rr[8];
            #pragma unroll
            for (int j = 0; j < 8; ++j)
                rr[j] = f2bf(tile[(quad * 8 + j) * 260 + y]);
            uint4 pk;
            pk.x = (unsigned)rr[0] | ((unsigned)rr[1] << 16);
            pk.y = (unsigned)rr[2] | ((unsigned)rr[3] << 16);
            pk.z = (unsigned)rr[4] | ((unsigned)rr[5] << 16);
            pk.w = (unsigned)rr[6] | ((unsigned)rr[7] << 16);
            *(uint4*)(Wf + ((size_t)yg * 256 + zg) * 512 + w * 8) = pk;
        }
    }
}

// ---- main fused kernel (v12) ----
__global__ __launch_bounds__(256, 2) void laplace_v12(
    const ushort* __restrict__ Xf, const ushort* __restrict__ Zf,
    const ushort* __restrict__ Wf, const float* __restrict__ xsqg,
    const float* __restrict__ zsqg, float* __restrict__ O)
{
    __shared__ ushort sM[16384 + 16896];          // 66,560 B total
    ushort* R1 = sM;                              // X k[0,256): 32 frags * 512
    ushort* R2 = sM + 16384;                      // X k[256,512) UNION sP[64][LDP]

    const int t = threadIdx.x, wid = t >> 6, lane = t & 63;
    const int l32 = lane & 31, hb = lane >> 5;

    // XCD-aware swizzle: z-chunk pinned to an XCD pair (grid = 512, 1-D)
    const int bid = blockIdx.x;
    const int xcd = bid & 7;
    const int chunk = xcd >> 1;                   // 0..3
    const int xi = ((xcd & 1) << 6) + (bid >> 3); // 0..127
    const int row0 = xi * BM;
    const int zbase = chunk * MPER;

    const unsigned lane_lo = (unsigned)(((l32 & 15) + 16 * hb) * 8);
    // X staging source base (frag f = 2*kw + i handled by wave wid, q=f-8*wid)
    const unsigned xsrc_base =
        (unsigned)(((row0 >> 4) + (l32 >> 4)) * 8192) + lane_lo;

    // ---- prologue: stage R1 (kw 0..15) and R2 (kw 16..31) once ----
    #pragma unroll
    for (int q = 0; q < 8; ++q) {
        const int f = wid * 8 + q;                // 0..31
        const int kw = f >> 1, i = f & 1;
        const ushort* s1 = Xf + xsrc_base + (unsigned)i * 16384u
                              + (unsigned)kw * 256u;
        gload_lds16(s1,            R1 + f * 512);
        gload_lds16(s1 + 4096u,    R2 + f * 512);   // +16 k-windows
    }

    f32x16 Oa[2][2];
    #pragma unroll
    for (int i = 0; i < 2; ++i)
        #pragma unroll
        for (int j = 0; j < 2; ++j)
            #pragma unroll
            for (int r = 0; r < 16; ++r) Oa[i][j][r] = 0.0f;

    asm volatile("s_waitcnt vmcnt(0)" ::: "memory");
    __syncthreads();                              // staging complete

    for (int mt = 0; mt < MT; ++mt) {
        // zsq for this wave's two 32-z frag columns
        const int zc0 = zbase + mt * 256 + wid * 64;
        const float zs0 = zsqg[zc0 + l32];
        const float zs1 = zsqg[zc0 + 32 + l32];

        f32x16 S[2][2];
        #pragma unroll
        for (int i = 0; i < 2; ++i)
            #pragma unroll
            for (int j = 0; j < 2; ++j)
                #pragma unroll
                for (int r = 0; r < 16; ++r) S[i][j][r] = 0.0f;

        // Z B-frag bases (kw-linear: +256 ushorts per k-window)
        const unsigned zg00 =
            (unsigned)((zbase >> 4) + mt * 16 + wid * 4 + (l32 >> 4));
        const unsigned zo0 = zg00 * 8192u + lane_lo;
        const unsigned zo1 = zo0 + 16384u;        // +2 row-groups (j=1)

        // ---- QK: 32 k-windows; h0 from R1 (never restaged), h1 from R2 ----
        #pragma unroll
        for (int h = 0; h < 2; ++h) {
            if (h == 1) {
                // B4: async h1 restage (issued last mt) complete everywhere
                asm volatile("s_waitcnt vmcnt(0)" ::: "memory");
                __syncthreads();
            }
            const ushort* XB = h ? R2 : R1;
            const unsigned kwb = (unsigned)(h * 16);
            frag8 xa[2][2], zb[2][2];
            #pragma unroll
            for (int p = 0; p < 2; ++p) {
                #pragma unroll
                for (int i = 0; i < 2; ++i)
                    xa[p][i] = *(const frag8*)(XB + (2 * p + i) * 512 + lane * 8);
                zb[p][0] = *(const frag8*)(Zf + zo0 + (kwb + p) * 256u);
                zb[p][1] = *(const frag8*)(Zf + zo1 + (kwb + p) * 256u);
            }
            #pragma unroll
            for (int kk = 0; kk < 16; ++kk) {
                const int cur = kk & 1;
                __builtin_amdgcn_s_setprio(1);
                S[0][0] = __builtin_amdgcn_mfma_f32_32x32x16_bf16(
                    xa[cur][0], zb[cur][0], S[0][0], 0, 0, 0);
                S[0][1] = __builtin_amdgcn_mfma_f32_32x32x16_bf16(
                    xa[cur][0], zb[cur][1], S[0][1], 0, 0, 0);
                S[1][0] = __builtin_amdgcn_mfma_f32_32x32x16_bf16(
                    xa[cur][1], zb[cur][0], S[1][0], 0, 0, 0);
                S[1][1] = __builtin_amdgcn_mfma_f32_32x32x16_bf16(
                    xa[cur][1], zb[cur][1], S[1][1], 0, 0, 0);
                __builtin_amdgcn_s_setprio(0);
                if (kk < 14) {                    // depth-2 prefetch
                    const int kn = kk + 2;
                    #pragma unroll
                    for (int i = 0; i < 2; ++i)
                        xa[cur][i] =
                            *(const frag8*)(XB + (2 * kn + i) * 512 + lane * 8);
                    zb[cur][0] = *(const frag8*)(Zf + zo0 + (kwb + kn) * 256u);
                    zb[cur][1] = *(const frag8*)(Zf + zo1 + (kwb + kn) * 256u);
                }
            }
        }

        __syncthreads();   // B1: all waves done reading R2 (X h1)

        // ---- transform S -> sP in R2 (C/D: col=l32, row=(r&3)+8*(r>>2)+4*hb)
        #pragma unroll
        for (int i = 0; i < 2; ++i) {
            float xv[16];
            #pragma unroll
            for (int g = 0; g < 4; ++g) {
                const float4 v =
                    *(const float4*)(xsqg + row0 + 32 * i + 8 * g + 4 * hb);
                xv[4 * g + 0] = v.x; xv[4 * g + 1] = v.y;
                xv[4 * g + 2] = v.z; xv[4 * g + 3] = v.w;
            }
            #pragma unroll
            for (int j = 0; j < 2; ++j) {
                const float zz = j ? zs1 : zs0;
                const int col = wid * 64 + 32 * j + l32;
                #pragma unroll
                for (int r = 0; r < 16; ++r) {
                    const int xrow = 32 * i + (r & 3) + 8 * (r >> 2) + 4 * hb;
                    const float xpz = xv[r] + zz;
                    float d2 = fmaf(S[i][j][r], -2.0f, xpz);
                    d2 = fmaxf(d2, 1e-20f);
                    const float dist = d2 * __frsqrt_rn(d2);     // sqrt(d2)
                    const float e = __builtin_amdgcn_exp2f(
                        dist * -0.14426950408889634f);           // exp(-dist/10)
                    R2[xrow * LDP + col] =
                        (ushort)(__builtin_bit_cast(unsigned, e) >> 16);
                }
            }
        }
        __syncthreads();   // B2: sP ready

        // ---- PV: O += P[64x256].W[256x256]; A from sP, B direct (Wf) ----
        const unsigned zwg0 = (unsigned)((zbase >> 4) + mt * 16);
        const unsigned wo0 =
            (unsigned)((wid * 4 + (l32 >> 4)) * 131072u) + zwg0 * 256u + lane_lo;
        const unsigned wo1 = wo0 + 262144u;       // jy=1: +2 y-row-groups
        const int pa0 = l32 * LDP + 8 * hb;
        frag8 pa[2][2], wb[2][2];
        #pragma unroll
        for (int p = 0; p < 2; ++p) {
            #pragma unroll
            for (int i = 0; i < 2; ++i)
                pa[p][i] = *(const frag8*)(R2 + pa0 + i * 32 * LDP + p * 16);
            wb[p][0] = *(const frag8*)(Wf + wo0 + (unsigned)p * 256u);
            wb[p][1] = *(const frag8*)(Wf + wo1 + (unsigned)p * 256u);
        }
        #pragma unroll
        for (int zw = 0; zw < 16; ++zw) {
            const int cur = zw & 1;
            __builtin_amdgcn_s_setprio(1);
            Oa[0][0] = __builtin_amdgcn_mfma_f32_32x32x16_bf16(
                pa[cur][0], wb[cur][0], Oa[0][0], 0, 0, 0);
            Oa[0][1] = __builtin_amdgcn_mfma_f32_32x32x16_bf16(
                pa[cur][0], wb[cur][1], Oa[0][1], 0, 0, 0);
            Oa[1][0] = __builtin_amdgcn_mfma_f32_32x32x16_bf16(
                pa[cur][1], wb[cur][0], Oa[1][0], 0, 0, 0);
            Oa[1][1] = __builtin_amdgcn_mfma_f32_32x32x16_bf16(
                pa[cur][1], wb[cur][1], Oa[1][1], 0, 0, 0);
            __builtin_amdgcn_s_setprio(0);
            if (zw < 14) {                        // depth-2 prefetch
                const int zn = zw + 2;
                #pragma unroll
                for (int i = 0; i < 2; ++i)
                    pa[cur][i] =
                        *(const frag8*)(R2 + pa0 + i * 32 * LDP + zn * 16);
                wb[cur][0] = *(const frag8*)(Wf + wo0 + (unsigned)zn * 256u);
                wb[cur][1] = *(const frag8*)(Wf + wo1 + (unsigned)zn * 256u);
            }
        }
        __syncthreads();   // B3: sP reads done, R2 free

        // ---- async restage of X h1 into R2 for next mt (lands under QK h0)
        if (mt + 1 < MT) {
            #pragma unroll
            for (int q = 0; q < 8; ++q) {
                const int f = wid * 8 + q;
                const int kw = (f >> 1) + 16, i = f & 1;
                gload_lds16(Xf + xsrc_base + (unsigned)i * 16384u
                               + (unsigned)kw * 256u,
                            R2 + f * 512);
            }
        }
    }

    // ---- epilogue: combine MCH=4 chunks via fp32 atomics (XCD-local) ----
    #pragma unroll
    for (int i = 0; i < 2; ++i)
        #pragma unroll
        for (int jy = 0; jy < 2; ++jy) {
            const int yg = wid * 64 + 32 * jy + l32;
            #pragma unroll
            for (int r = 0; r < 16; ++r) {
                const int xg = row0 + 32 * i + (r & 3) + 8 * (r >> 2) + 4 * hb;
                atomicAdd(&O[(size_t)xg * Yd + yg], Oa[i][jy][r]);
            }
        }
}

// ---- fallback (fp32 VALU fused kernel) if workspace is too small ----
constexpr int FBM = 64, FBN = 64, FBK = 64;
constexpr int FMCH = 4, FMCHUNK = Mm / FMCH, FMSTEPS = FMCHUNK / FBN, FDSTEPS = Dd / FBK;
constexpr int FLDA = FBK + 1, FLDSS = FBN + 1;

__global__ __launch_bounds__(256, 3) void laplace_fused_v1(
    const float* __restrict__ X, const float* __restrict__ Z,
    const float* __restrict__ W, float* __restrict__ O)
{
    __shared__ float sX[FBM * FLDA];
    __shared__ float sZ[FBN * FLDA];
    __shared__ float sS[FBM * FLDSS];
    const int t = threadIdx.x, pr = t >> 4, pc = t & 15, sc4 = pc * 4;
    const int row0 = blockIdx.x * FBM, mbase = blockIdx.y * FMCHUNK;
    float o[4][4][4];
    #pragma unroll
    for (int i = 0; i < 4; ++i)
        for (int yb = 0; yb < 4; ++yb)
            for (int j = 0; j < 4; ++j) o[i][yb][j] = 0.0f;
    for (int ms = 0; ms < FMSTEPS; ++ms) {
        const int zrow0 = mbase + ms * FBN;
        float s[4][4];
        #pragma unroll
        for (int i = 0; i < 4; ++i)
            for (int j = 0; j < 4; ++j) s[i][j] = 0.0f;
        for (int kk = 0; kk < FDSTEPS; ++kk) {
            const int k0 = kk * FBK;
            __syncthreads();
            #pragma unroll
            for (int rep = 0; rep < 4; ++rep) {
                const int r = pr + rep * 16;
                const float4 xv = *reinterpret_cast<const float4*>(X + (size_t)(row0 + r) * Dd + k0 + sc4);
                const float4 zv = *reinterpret_cast<const float4*>(Z + (size_t)(zrow0 + r) * Dd + k0 + sc4);
                float* dx = sX + r * FLDA + sc4;
                dx[0] = xv.x; dx[1] = xv.y; dx[2] = xv.z; dx[3] = xv.w;
                float* dz = sZ + r * FLDA + sc4;
                dz[0] = zv.x; dz[1] = zv.y; dz[2] = zv.z; dz[3] = zv.w;
            }
            __syncthreads();
            #pragma unroll 4
            for (int k = 0; k < FBK; ++k) {
                float xr[4], zc[4];
                #pragma unroll
                for (int i = 0; i < 4; ++i) xr[i] = sX[(pr * 4 + i) * FLDA + k];
                #pragma unroll
                for (int j = 0; j < 4; ++j) zc[j] = sZ[(pc * 4 + j) * FLDA + k];
                #pragma unroll
                for (int i = 0; i < 4; ++i)
                    #pragma unroll
                    for (int j = 0; j < 4; ++j) {
                        const float d = xr[i] - zc[j];
                        s[i][j] = fmaf(d, d, s[i][j]);
                    }
            }
        }
        #pragma unroll
        for (int i = 0; i < 4; ++i)
            for (int j = 0; j < 4; ++j)
                sS[(pr * 4 + i) * FLDSS + sc4 + j] = __expf(-sqrtf(s[i][j]) * 0.1f);
        __syncthreads();
        #pragma unroll 2
        for (int c = 0; c < FBN; ++c) {
            float sv[4];
            #pragma unroll
            for (int i = 0; i < 4; ++i) sv[i] = sS[(pr * 4 + i) * FLDSS + c];
            const float* wrow = W + (size_t)(zrow0 + c) * Yd;
            #pragma unroll
            for (int yb = 0; yb < 4; ++yb) {
                const float4 wv = *reinterpret_cast<const float4*>(wrow + yb * 64 + sc4);
                #pragma unroll
                for (int i = 0; i < 4; ++i) {
                    o[i][yb][0] = fmaf(sv[i], wv.x, o[i][yb][0]);
                    o[i][yb][1] = fmaf(sv[i], wv.y, o[i][yb][1]);
                    o[i][yb][2] = fmaf(sv[i], wv.z, o[i][yb][2]);
                    o[i][yb][3] = fmaf(sv[i], wv.w, o[i][yb][3]);
                }
            }
        }
        __syncthreads();
    }
    #pragma unroll
    for (int i = 0; i < 4; ++i) {
        const size_t rbase = (size_t)(row0 + pr * 4 + i) * Yd;
        #pragma unroll
        for (int yb = 0; yb < 4; ++yb)
            for (int j = 0; j < 4; ++j)
                atomicAdd(O + rbase + yb * 64 + sc4 + j, o[i][yb][j]);
    }
}

extern "C" void kernel_launch(void* const* d_in, const int* in_sizes, int n_in,
                              void* d_out, int out_size, void* d_ws, size_t ws_size,
                              hipStream_t stream) {
    const float* X = (const float*)d_in[0];   // batch   [8192, 512]
    const float* Z = (const float*)d_in[1];   // centers [8192, 512]
    const float* W = (const float*)d_in[2];   // weight  [8192, 256]
    float* O = (float*)d_out;                 // pred    [8192, 256]

    hipMemsetAsync(d_out, 0, (size_t)out_size * sizeof(float), stream);

    if (ws_size < WS_NEED) {
        dim3 grid(Nn / FBM, FMCH);
        laplace_fused_v1<<<grid, dim3(256), 0, stream>>>(X, Z, W, O);
        return;
    }

    char* ws = (char*)d_ws;
    ushort* Xf  = (ushort*)(ws + OFF_XF);
    ushort* Zf  = (ushort*)(ws + OFF_ZF);
    ushort* Wf  = (ushort*)(ws + OFF_WF);
    float*  xsq = (float*)(ws + OFF_XSQ);
    float*  zsq = (float*)(ws + OFF_ZSQ);

    prep_v11<<<dim3(1024 + 256), dim3(256), 0, stream>>>(
        X, Z, W, Xf, Zf, Wf, xsq, zsq);

    laplace_v12<<<dim3(512), dim3(256), 0, stream>>>(
        Xf, Zf, Wf, xsq, zsq, O);
}